// Round 3
// baseline (338.271 us; speedup 1.0000x reference)
//
#include <hip/hip_runtime.h>
#include <hip/hip_bf16.h>

typedef short s8v __attribute__((ext_vector_type(8)));
typedef float f4v __attribute__((ext_vector_type(4)));

#define MFMA_BF16 __builtin_amdgcn_mfma_f32_16x16x32_bf16

// LDS element offsets (16-bit elements), staging only (loop is LDS-free).
constexpr int OFF_W0T  = 0;      // [64][40]  Ws0^T, k<32
constexpr int OFF_W1T  = 2560;   // [64][72]  Ws1^T
constexpr int OFF_W2T  = 7168;   // [16][72]  Ws2^T
constexpr int OFF_WC0T = 8320;   // [64][72]  Wc0^T: k<32=d rows, k=32 zero,
                                 //           k in [33,48) = geo rows, k>=48 zero
constexpr int OFF_WC1T = 12928;  // [64][72]
constexpr int OFF_WC2T = 17536;  // [64][72]
constexpr int OFF_WC3T = 22144;  // [16][72]  zero rows n>=3
constexpr int SMEM_EL  = 23296;  // 46592 B (prologue only)

static __device__ __forceinline__ short bf2s(__hip_bfloat16 h) {
    union { __hip_bfloat16 b; short s; } u; u.b = h; return u.s;
}

__global__ __launch_bounds__(512, 2)
void rf_fused(const void* __restrict__ xv,
              const void* __restrict__ dv,
              const void* __restrict__ Ws0,
              const void* __restrict__ Ws1,
              const void* __restrict__ Ws2,
              const void* __restrict__ Wc0,
              const void* __restrict__ Wc1,
              const void* __restrict__ Wc2,
              const void* __restrict__ Wc3,
              void* __restrict__ outp,
              int npts)
{
    __shared__ __align__(16) short smem[SMEM_EL];
    __shared__ int cls_cnt;
    const int t = threadIdx.x;

    // ---- input dtype self-detection ----
    if (t == 0) cls_cnt = 0;
    __syncthreads();
    {
        unsigned short w = ((const unsigned short*)xv)[2 * t];
        int e = (w >> 7) & 0xFF;
        if (e >= 110 && e <= 140) atomicAdd(&cls_cnt, 1);
    }
    __syncthreads();
    const bool isbf = (cls_cnt >= 256);

    auto ldw = [&](const void* p, int idx) -> short {
        if (isbf) return ((const short*)p)[idx];
        return bf2s(__float2bfloat16(((const float*)p)[idx]));
    };

    // ---- stage weights transposed: sW[n][k] = W[k][n] ----
    for (int i = t; i < 2048; i += 512) { int k = i >> 6, n = i & 63; smem[OFF_W0T  + n*40 + k] = ldw(Ws0, i); }
    for (int i = t; i < 4096; i += 512) { int k = i >> 6, n = i & 63; smem[OFF_W1T  + n*72 + k] = ldw(Ws1, i); }
    for (int i = t; i < 1024; i += 512) { int k = i >> 4, n = i & 15; smem[OFF_W2T  + n*72 + k] = ldw(Ws2, i); }
    // Wc0: rows 0..31 at k=row (d); rows 32..46 at k=row+1 (geo, shifted);
    // k=32 and k>=48 are zero rows. This absorbs the geo feature shift so the
    // color-net k in [32,64) B-fragment equals the raw redist of the sigma L3 tile.
    for (int i = t; i < 4096; i += 512) {
        int n = i >> 6, k = i & 63;
        short v = 0;
        if (k < 32)                 v = ldw(Wc0, k*64 + n);
        else if (k >= 33 && k < 48) v = ldw(Wc0, (k-1)*64 + n);
        smem[OFF_WC0T + n*72 + k] = v;
    }
    for (int i = t; i < 4096; i += 512) { int k = i >> 6, n = i & 63; smem[OFF_WC1T + n*72 + k] = ldw(Wc1, i); }
    for (int i = t; i < 4096; i += 512) { int k = i >> 6, n = i & 63; smem[OFF_WC2T + n*72 + k] = ldw(Wc2, i); }
    for (int i = t; i < 1024; i += 512) { int n = i >> 6, k = i & 63; smem[OFF_WC3T + n*72 + k] = (n < 3) ? ldw(Wc3, k*3 + n) : (short)0; }
    __syncthreads();

    const int lane = t & 63;
    const int wv   = t >> 6;
    const int m16  = lane & 15;   // point within 16-tile (B/D column)
    const int q    = lane >> 4;   // quad: k-group for A/B, feature-row-group for D

    const f4v zf = {0.f, 0.f, 0.f, 0.f};

    // ---- hoist ALL weight A-fragments into registers (loop-invariant) ----
    s8v w0f[4], w1f[4][2], wc0f[4][2], wc1f[4][2], wc2f[4][2], w2f[2], wc3f[2];
    #pragma unroll
    for (int kt = 0; kt < 4; kt++) {
        w0f[kt] = *(const s8v*)(smem + OFF_W0T + (kt*16 + m16)*40 + q*8);
        #pragma unroll
        for (int h = 0; h < 2; h++) {
            w1f[kt][h]  = *(const s8v*)(smem + OFF_W1T  + (kt*16 + m16)*72 + h*32 + q*8);
            wc0f[kt][h] = *(const s8v*)(smem + OFF_WC0T + (kt*16 + m16)*72 + h*32 + q*8);
            wc1f[kt][h] = *(const s8v*)(smem + OFF_WC1T + (kt*16 + m16)*72 + h*32 + q*8);
            wc2f[kt][h] = *(const s8v*)(smem + OFF_WC2T + (kt*16 + m16)*72 + h*32 + q*8);
        }
    }
    #pragma unroll
    for (int h = 0; h < 2; h++) {
        w2f[h]  = *(const s8v*)(smem + OFF_W2T  + m16*72 + h*32 + q*8);
        wc3f[h] = *(const s8v*)(smem + OFF_WC3T + m16*72 + h*32 + q*8);
    }

    auto loadRow8f = [&](const void* p, int eoff) -> s8v {
        const float* f = (const float*)p + eoff;
        f4v f0 = *(const f4v*)f;
        f4v f1 = *(const f4v*)(f + 4);
        s8v r;
        #pragma unroll
        for (int j = 0; j < 4; j++) {
            r[j]     = bf2s(__float2bfloat16(f0[j]));
            r[j + 4] = bf2s(__float2bfloat16(f1[j]));
        }
        return r;
    };
    auto putOut = [&](int idx, float v) {
        if (isbf) ((short*)outp)[idx] = bf2s(__float2bfloat16(v));
        else      ((float*)outp)[idx] = v;
    };

    // ---- in-register feature redistribution (relu fused) ----
    // Input: a[kt][r] = H^T output, feature f = kt*16 + q*4 + r, one point/lane.
    // Output: fr[kc] = B-fragment, element j = bf16 of feature kc*32 + q*8 + j.
    auto redist = [&](const f4v (&a)[4], s8v (&fr)[2]) {
        unsigned int P[4][2];
        #pragma unroll
        for (int kt = 0; kt < 4; kt++)
            #pragma unroll
            for (int rp = 0; rp < 2; rp++) {
                float lo = fmaxf(a[kt][2*rp],     0.f);
                float hi = fmaxf(a[kt][2*rp + 1], 0.f);
                union { __hip_bfloat162 b; unsigned int u; } cu;
                cu.b = __float22bfloat162_rn(float2{lo, hi});
                P[kt][rp] = cu.u;
            }
        #pragma unroll
        for (int a2 = 0; a2 < 2; a2++)
            #pragma unroll
            for (int rp = 0; rp < 2; rp++) {
                asm("v_permlane32_swap_b32 %0, %1" : "+v"(P[2*a2][rp]), "+v"(P[2*a2+1][rp]));
                asm("v_permlane16_swap_b32 %0, %1" : "+v"(P[2*a2][rp]), "+v"(P[2*a2+1][rp]));
            }
        #pragma unroll
        for (int kc = 0; kc < 2; kc++) {
            union { unsigned int u[4]; s8v v; } fu;
            fu.u[0] = P[2*kc][0];     fu.u[1] = P[2*kc][1];
            fu.u[2] = P[2*kc + 1][0]; fu.u[3] = P[2*kc + 1][1];
            fr[kc] = fu.v;
        }
    };

    // 64-out layer, all operands in registers
    auto layerR = [&](const s8v (&wf)[4][2], const s8v (&bfr)[2][2], f4v (&out)[2][4]) {
        #pragma unroll
        for (int kt = 0; kt < 4; kt++)
            #pragma unroll
            for (int pt = 0; pt < 2; pt++)
                out[pt][kt] = MFMA_BF16(wf[kt][1], bfr[pt][1],
                              MFMA_BF16(wf[kt][0], bfr[pt][0], zf, 0,0,0), 0,0,0);
    };

    const int ntiles = npts / 32;
    const int tstep  = gridDim.x * 8;
    int tile = blockIdx.x * 8 + wv;

    // prologue loads (bf16 fast path; fp32 path loads in-loop)
    s8v xb[2], db[2];
    if (isbf && tile < ntiles) {
        #pragma unroll
        for (int pt = 0; pt < 2; pt++) {
            const int off = (tile*32 + pt*16 + m16)*32 + q*8;
            xb[pt] = *(const s8v*)((const short*)xv + off);
            db[pt] = *(const s8v*)((const short*)dv + off);
        }
    }

    #pragma unroll 1
    for (; tile < ntiles; tile += tstep) {
        const int r0  = tile * 32;
        const int nxt = tile + tstep;

        if (!isbf) {
            #pragma unroll
            for (int pt = 0; pt < 2; pt++) {
                const int off = (r0 + pt*16 + m16)*32 + q*8;
                xb[pt] = loadRow8f(xv, off);
                db[pt] = loadRow8f(dv, off);
            }
        }

        f4v acc[2][4];
        s8v bfr[2][2];

        // ---------------- sigma net (transposed) ----------------
        // L1: H1^T = Ws0^T(64x32) @ X^T(32x32)
        #pragma unroll
        for (int kt = 0; kt < 4; kt++)
            #pragma unroll
            for (int pt = 0; pt < 2; pt++)
                acc[pt][kt] = MFMA_BF16(w0f[kt], xb[pt], zf, 0,0,0);

        // xb consumed: single-buffer prefetch next tile's x (latency hides under 6 layers)
        if (isbf && nxt < ntiles) {
            #pragma unroll
            for (int pt = 0; pt < 2; pt++)
                xb[pt] = *(const s8v*)((const short*)xv + (nxt*32 + pt*16 + m16)*32 + q*8);
        }

        #pragma unroll
        for (int pt = 0; pt < 2; pt++) redist(acc[pt], bfr[pt]);

        // L2
        layerR(w1f, bfr, acc);
        #pragma unroll
        for (int pt = 0; pt < 2; pt++) redist(acc[pt], bfr[pt]);

        // L3: H3^T(16x32) = Ws2^T(16x64) @ H2^T
        f4v s3[2];
        #pragma unroll
        for (int pt = 0; pt < 2; pt++)
            s3[pt] = MFMA_BF16(w2f[1], bfr[pt][1],
                     MFMA_BF16(w2f[0], bfr[pt][0], zf, 0,0,0), 0,0,0);

        // sigma out: feature 0 = lanes q==0, r==0
        if (q == 0) {
            #pragma unroll
            for (int pt = 0; pt < 2; pt++)
                putOut(3*npts + r0 + pt*16 + m16, fmaxf(s3[pt][0], 0.f));
        }

        // ---------------- junction (no LDS) ----------------
        // Place s3 at kt=2 of a duplicated input; standard redist then yields
        // fr[1] = features 32..63 where 32+f holds H3 feature f (relu'd).
        // Duplicate slots give finite values that meet zero weight rows.
        #pragma unroll
        for (int pt = 0; pt < 2; pt++) {
            f4v sd[4] = { s3[pt], s3[pt], s3[pt], s3[pt] };
            s8v fj[2];
            redist(sd, fj);
            bfr[pt][1] = fj[1];
            bfr[pt][0] = db[pt];
        }

        // ---------------- color net ----------------
        // C0: Hc1^T = Wc0^T @ [d | geo]^T
        layerR(wc0f, bfr, acc);

        // db consumed: prefetch next tile's d (latency hides under C1..C3)
        if (isbf && nxt < ntiles) {
            #pragma unroll
            for (int pt = 0; pt < 2; pt++)
                db[pt] = *(const s8v*)((const short*)dv + (nxt*32 + pt*16 + m16)*32 + q*8);
        }

        #pragma unroll
        for (int pt = 0; pt < 2; pt++) redist(acc[pt], bfr[pt]);

        // C1
        layerR(wc1f, bfr, acc);
        #pragma unroll
        for (int pt = 0; pt < 2; pt++) redist(acc[pt], bfr[pt]);

        // C2
        layerR(wc2f, bfr, acc);
        #pragma unroll
        for (int pt = 0; pt < 2; pt++) redist(acc[pt], bfr[pt]);

        // C3: RGB^T(16x32) = Wc3^T(16x64) @ Hc3^T
        f4v c7[2];
        #pragma unroll
        for (int pt = 0; pt < 2; pt++)
            c7[pt] = MFMA_BF16(wc3f[1], bfr[pt][1],
                     MFMA_BF16(wc3f[0], bfr[pt][0], zf, 0,0,0), 0,0,0);

        if (q == 0) {
            #pragma unroll
            for (int pt = 0; pt < 2; pt++) {
                const int base = (r0 + pt*16 + m16) * 3;
                #pragma unroll
                for (int r = 0; r < 3; r++) {
                    float v  = c7[pt][r];
                    float sg = 1.0f / (1.0f + __expf(-v));
                    putOut(base + r, sg);
                }
            }
        }
    }
}

extern "C" void kernel_launch(void* const* d_in, const int* in_sizes, int n_in,
                              void* d_out, int out_size, void* d_ws, size_t ws_size,
                              hipStream_t stream) {
    const int npts = in_sizes[0] / 32;
    // 512 blocks x 512 thr; ~240 VGPR -> 2 waves/SIMD (8 waves/CU), loop is LDS-free.
    rf_fused<<<512, 512, 0, stream>>>(d_in[0], d_in[1], d_in[2], d_in[3], d_in[4],
                                      d_in[5], d_in[6], d_in[7], d_in[8],
                                      d_out, npts);
}

// Round 4
// 325.019 us; speedup vs baseline: 1.0408x; 1.0408x over previous
//
#include <hip/hip_runtime.h>
#include <hip/hip_bf16.h>

typedef short s8v __attribute__((ext_vector_type(8)));
typedef float f4v __attribute__((ext_vector_type(4)));

#define MFMA_BF16 __builtin_amdgcn_mfma_f32_16x16x32_bf16

// LDS element offsets (16-bit elements). Weights only; loop activations stay in regs.
constexpr int OFF_W0T  = 0;      // [64][40]  Ws0^T, k<32
constexpr int OFF_W1T  = 2560;   // [64][72]  Ws1^T
constexpr int OFF_W2T  = 7168;   // [16][72]  Ws2^T
constexpr int OFF_WC0T = 8320;   // [64][72]  Wc0^T: k<32=d rows, k=32 zero,
                                 //           k in [33,48) = geo rows, k>=48 zero
constexpr int OFF_WC1T = 12928;  // [64][72]
constexpr int OFF_WC2T = 17536;  // [64][72]
constexpr int OFF_WC3T = 22144;  // [16][72]  zero rows n>=3
constexpr int SMEM_EL  = 23296;  // 46592 B -> 3 blocks/CU (24 waves/CU)

static __device__ __forceinline__ short bf2s(__hip_bfloat16 h) {
    union { __hip_bfloat16 b; short s; } u; u.b = h; return u.s;
}

__global__ __launch_bounds__(512, 6)
void rf_fused(const void* __restrict__ xv,
              const void* __restrict__ dv,
              const void* __restrict__ Ws0,
              const void* __restrict__ Ws1,
              const void* __restrict__ Ws2,
              const void* __restrict__ Wc0,
              const void* __restrict__ Wc1,
              const void* __restrict__ Wc2,
              const void* __restrict__ Wc3,
              void* __restrict__ outp,
              int npts)
{
    __shared__ __align__(16) short smem[SMEM_EL];
    __shared__ int cls_cnt;
    const int t = threadIdx.x;

    // ---- input dtype self-detection ----
    if (t == 0) cls_cnt = 0;
    __syncthreads();
    {
        unsigned short w = ((const unsigned short*)xv)[2 * t];
        int e = (w >> 7) & 0xFF;
        if (e >= 110 && e <= 140) atomicAdd(&cls_cnt, 1);
    }
    __syncthreads();
    const bool isbf = (cls_cnt >= 256);

    auto ldw = [&](const void* p, int idx) -> short {
        if (isbf) return ((const short*)p)[idx];
        return bf2s(__float2bfloat16(((const float*)p)[idx]));
    };

    // ---- stage weights transposed: sW[n][k] = W[k][n] ----
    for (int i = t; i < 2048; i += 512) { int k = i >> 6, n = i & 63; smem[OFF_W0T  + n*40 + k] = ldw(Ws0, i); }
    for (int i = t; i < 4096; i += 512) { int k = i >> 6, n = i & 63; smem[OFF_W1T  + n*72 + k] = ldw(Ws1, i); }
    for (int i = t; i < 1024; i += 512) { int k = i >> 4, n = i & 15; smem[OFF_W2T  + n*72 + k] = ldw(Ws2, i); }
    // Wc0: rows 0..31 at k=row (d); rows 32..46 at k=row+1 (geo, shifted);
    // k=32 and k>=48 zero. Absorbs the geo feature shift so the color-net
    // k in [32,64) B-fragment equals the raw redist of the sigma L3 tile.
    for (int i = t; i < 4096; i += 512) {
        int n = i >> 6, k = i & 63;
        short v = 0;
        if (k < 32)                 v = ldw(Wc0, k*64 + n);
        else if (k >= 33 && k < 48) v = ldw(Wc0, (k-1)*64 + n);
        smem[OFF_WC0T + n*72 + k] = v;
    }
    for (int i = t; i < 4096; i += 512) { int k = i >> 6, n = i & 63; smem[OFF_WC1T + n*72 + k] = ldw(Wc1, i); }
    for (int i = t; i < 4096; i += 512) { int k = i >> 6, n = i & 63; smem[OFF_WC2T + n*72 + k] = ldw(Wc2, i); }
    for (int i = t; i < 1024; i += 512) { int n = i >> 6, k = i & 63; smem[OFF_WC3T + n*72 + k] = (n < 3) ? ldw(Wc3, k*3 + n) : (short)0; }
    __syncthreads();

    const int lane = t & 63;
    const int wv   = t >> 6;
    const int m16  = lane & 15;   // point within 16-tile (B/D column)
    const int q    = lane >> 4;   // quad: k-group for A/B, feature-row-group for D

    const f4v zf = {0.f, 0.f, 0.f, 0.f};

    auto loadRow8f = [&](const void* p, int eoff) -> s8v {
        const float* f = (const float*)p + eoff;
        f4v f0 = *(const f4v*)f;
        f4v f1 = *(const f4v*)(f + 4);
        s8v r;
        #pragma unroll
        for (int j = 0; j < 4; j++) {
            r[j]     = bf2s(__float2bfloat16(f0[j]));
            r[j + 4] = bf2s(__float2bfloat16(f1[j]));
        }
        return r;
    };
    auto putOut = [&](int idx, float v) {
        if (isbf) ((short*)outp)[idx] = bf2s(__float2bfloat16(v));
        else      ((float*)outp)[idx] = v;
    };

    // hardware packed f32x2 -> bf16x2 (RNE); no builtin on gfx950, use asm
    auto cvtpk = [](float lo, float hi) -> unsigned int {
        unsigned int r;
        asm("v_cvt_pk_bf16_f32 %0, %1, %2" : "=v"(r) : "v"(lo), "v"(hi));
        return r;
    };

    // ---- in-register feature redistribution (relu fused) ----
    // Input: a[kt][r] = H^T output, feature f = kt*16 + q*4 + r, one point/lane.
    // Output: fr[kc] = B-fragment, element j = bf16 of feature kc*32 + q*8 + j.
    auto redist = [&](const f4v (&a)[4], s8v (&fr)[2]) {
        unsigned int P[4][2];
        #pragma unroll
        for (int kt = 0; kt < 4; kt++)
            #pragma unroll
            for (int rp = 0; rp < 2; rp++)
                P[kt][rp] = cvtpk(fmaxf(a[kt][2*rp], 0.f), fmaxf(a[kt][2*rp+1], 0.f));
        #pragma unroll
        for (int a2 = 0; a2 < 2; a2++)
            #pragma unroll
            for (int rp = 0; rp < 2; rp++) {
                asm("v_permlane32_swap_b32 %0, %1" : "+v"(P[2*a2][rp]), "+v"(P[2*a2+1][rp]));
                asm("v_permlane16_swap_b32 %0, %1" : "+v"(P[2*a2][rp]), "+v"(P[2*a2+1][rp]));
            }
        #pragma unroll
        for (int kc = 0; kc < 2; kc++) {
            union { unsigned int u[4]; s8v v; } fu;
            fu.u[0] = P[2*kc][0];     fu.u[1] = P[2*kc][1];
            fu.u[2] = P[2*kc + 1][0]; fu.u[3] = P[2*kc + 1][1];
            fr[kc] = fu.v;
        }
    };
    // junction: only the kc=1 fragment of redist with all kt slots = s
    auto redistHalf = [&](const f4v s, s8v &frHi) {
        unsigned int P2[2], P3[2];
        #pragma unroll
        for (int rp = 0; rp < 2; rp++) {
            P2[rp] = cvtpk(fmaxf(s[2*rp], 0.f), fmaxf(s[2*rp+1], 0.f));
            P3[rp] = P2[rp];
        }
        #pragma unroll
        for (int rp = 0; rp < 2; rp++) {
            asm("v_permlane32_swap_b32 %0, %1" : "+v"(P2[rp]), "+v"(P3[rp]));
            asm("v_permlane16_swap_b32 %0, %1" : "+v"(P2[rp]), "+v"(P3[rp]));
        }
        union { unsigned int u[4]; s8v v; } fu;
        fu.u[0] = P2[0]; fu.u[1] = P2[1]; fu.u[2] = P3[0]; fu.u[3] = P3[1];
        frHi = fu.v;
    };

    // 64-out transposed layer: W^T from LDS (A-operand), activations in regs (B)
    auto layerT = [&](int woff, const s8v (&bfr)[2][2], f4v (&out)[2][4]) {
        #pragma unroll
        for (int kt = 0; kt < 4; kt++) {
            s8v a0 = *(const s8v*)(smem + woff + (kt*16 + m16)*72 + q*8);
            s8v a1 = *(const s8v*)(smem + woff + (kt*16 + m16)*72 + 32 + q*8);
            #pragma unroll
            for (int pt = 0; pt < 2; pt++)
                out[pt][kt] = MFMA_BF16(a1, bfr[pt][1],
                              MFMA_BF16(a0, bfr[pt][0], zf, 0,0,0), 0,0,0);
        }
    };

    const int ntiles = npts / 32;
    const int tstep  = gridDim.x * 8;
    int tile = blockIdx.x * 8 + wv;

    // prologue loads (bf16 fast path; fp32 path loads in-loop)
    s8v xb[2], db[2];
    if (isbf && tile < ntiles) {
        #pragma unroll
        for (int pt = 0; pt < 2; pt++) {
            const int off = (tile*32 + pt*16 + m16)*32 + q*8;
            xb[pt] = *(const s8v*)((const short*)xv + off);
            db[pt] = *(const s8v*)((const short*)dv + off);
        }
    }

    #pragma unroll 1
    for (; tile < ntiles; tile += tstep) {
        const int r0  = tile * 32;
        const int nxt = tile + tstep;

        if (!isbf) {
            #pragma unroll
            for (int pt = 0; pt < 2; pt++) {
                const int off = (r0 + pt*16 + m16)*32 + q*8;
                xb[pt] = loadRow8f(xv, off);
                db[pt] = loadRow8f(dv, off);
            }
        }

        f4v acc[2][4];
        s8v bfr[2][2];

        // ---------------- sigma net (transposed) ----------------
        // L1: H1^T = Ws0^T(64x32) @ X^T(32x32)
        #pragma unroll
        for (int kt = 0; kt < 4; kt++) {
            s8v a0 = *(const s8v*)(smem + OFF_W0T + (kt*16 + m16)*40 + q*8);
            #pragma unroll
            for (int pt = 0; pt < 2; pt++)
                acc[pt][kt] = MFMA_BF16(a0, xb[pt], zf, 0,0,0);
        }

        // xb consumed: single-buffer prefetch next tile's x (hides under 6 layers)
        if (isbf && nxt < ntiles) {
            #pragma unroll
            for (int pt = 0; pt < 2; pt++)
                xb[pt] = *(const s8v*)((const short*)xv + (nxt*32 + pt*16 + m16)*32 + q*8);
        }

        #pragma unroll
        for (int pt = 0; pt < 2; pt++) redist(acc[pt], bfr[pt]);

        // L2
        layerT(OFF_W1T, bfr, acc);
        #pragma unroll
        for (int pt = 0; pt < 2; pt++) redist(acc[pt], bfr[pt]);

        // L3: H3^T(16x32) = Ws2^T(16x64) @ H2^T
        f4v s3[2];
        {
            s8v c0 = *(const s8v*)(smem + OFF_W2T + m16*72 + q*8);
            s8v c1 = *(const s8v*)(smem + OFF_W2T + m16*72 + 32 + q*8);
            #pragma unroll
            for (int pt = 0; pt < 2; pt++)
                s3[pt] = MFMA_BF16(c1, bfr[pt][1],
                         MFMA_BF16(c0, bfr[pt][0], zf, 0,0,0), 0,0,0);
        }

        // sigma out: feature 0 = lanes q==0, r==0
        if (q == 0) {
            #pragma unroll
            for (int pt = 0; pt < 2; pt++)
                putOut(3*npts + r0 + pt*16 + m16, fmaxf(s3[pt][0], 0.f));
        }

        // ---------------- junction (no LDS) ----------------
        // Redistribute s3 into the k in [32,64) B-fragment slot; the Wc0
        // staging's zero rows null everything except geo features 1..15.
        #pragma unroll
        for (int pt = 0; pt < 2; pt++) {
            redistHalf(s3[pt], bfr[pt][1]);
            bfr[pt][0] = db[pt];
        }

        // ---------------- color net ----------------
        // C0: Hc1^T = Wc0^T @ [d | geo]^T
        layerT(OFF_WC0T, bfr, acc);

        // db consumed: prefetch next tile's d (hides under C1..C3)
        if (isbf && nxt < ntiles) {
            #pragma unroll
            for (int pt = 0; pt < 2; pt++)
                db[pt] = *(const s8v*)((const short*)dv + (nxt*32 + pt*16 + m16)*32 + q*8);
        }

        #pragma unroll
        for (int pt = 0; pt < 2; pt++) redist(acc[pt], bfr[pt]);

        // C1
        layerT(OFF_WC1T, bfr, acc);
        #pragma unroll
        for (int pt = 0; pt < 2; pt++) redist(acc[pt], bfr[pt]);

        // C2
        layerT(OFF_WC2T, bfr, acc);
        #pragma unroll
        for (int pt = 0; pt < 2; pt++) redist(acc[pt], bfr[pt]);

        // C3: RGB^T(16x32) = Wc3^T(16x64) @ Hc3^T
        f4v c7[2];
        {
            s8v e0 = *(const s8v*)(smem + OFF_WC3T + m16*72 + q*8);
            s8v e1 = *(const s8v*)(smem + OFF_WC3T + m16*72 + 32 + q*8);
            #pragma unroll
            for (int pt = 0; pt < 2; pt++)
                c7[pt] = MFMA_BF16(e1, bfr[pt][1],
                         MFMA_BF16(e0, bfr[pt][0], zf, 0,0,0), 0,0,0);
        }
        if (q == 0) {
            #pragma unroll
            for (int pt = 0; pt < 2; pt++) {
                const int base = (r0 + pt*16 + m16) * 3;
                #pragma unroll
                for (int r = 0; r < 3; r++) {
                    float v  = c7[pt][r];
                    float sg = 1.0f / (1.0f + __expf(-v));
                    putOut(base + r, sg);
                }
            }
        }
    }
}

extern "C" void kernel_launch(void* const* d_in, const int* in_sizes, int n_in,
                              void* d_out, int out_size, void* d_ws, size_t ws_size,
                              hipStream_t stream) {
    const int npts = in_sizes[0] / 32;
    // 768 blocks x 512 thr = exactly 3 blocks/CU (46.6 KB LDS), 24 waves/CU,
    // 6 waves/SIMD; all waves resident, 5-6 tiles per wave.
    rf_fused<<<768, 512, 0, stream>>>(d_in[0], d_in[1], d_in[2], d_in[3], d_in[4],
                                      d_in[5], d_in[6], d_in[7], d_in[8],
                                      d_out, npts);
}

// Round 5
// 319.292 us; speedup vs baseline: 1.0594x; 1.0179x over previous
//
#include <hip/hip_runtime.h>
#include <hip/hip_bf16.h>

typedef short s8v __attribute__((ext_vector_type(8)));
typedef float f4v __attribute__((ext_vector_type(4)));

#define MFMA_BF16 __builtin_amdgcn_mfma_f32_16x16x32_bf16

// LDS element offsets (16-bit elements). Weights only; loop activations in regs.
constexpr int OFF_W0T  = 0;      // [64][40]  Ws0^T, k<32
constexpr int OFF_W1T  = 2560;   // [64][72]  Ws1^T
constexpr int OFF_W2T  = 7168;   // [16][72]  Ws2^T
constexpr int OFF_WC0T = 8320;   // [64][72]  Wc0^T: k<32=d rows, k=32 zero,
                                 //           k in [33,48) = geo rows, k>=48 zero
constexpr int OFF_WC1T = 12928;  // [64][72]
constexpr int OFF_WC2T = 17536;  // [64][72]
constexpr int OFF_WC3T = 22144;  // [16][72]  zero rows n>=3
constexpr int SMEM_EL  = 23296;  // 46592 B

static __device__ __forceinline__ short bf2s(__hip_bfloat16 h) {
    union { __hip_bfloat16 b; short s; } u; u.b = h; return u.s;
}

__global__ __launch_bounds__(512, 4)
void rf_fused(const void* __restrict__ xv,
              const void* __restrict__ dv,
              const void* __restrict__ Ws0,
              const void* __restrict__ Ws1,
              const void* __restrict__ Ws2,
              const void* __restrict__ Wc0,
              const void* __restrict__ Wc1,
              const void* __restrict__ Wc2,
              const void* __restrict__ Wc3,
              void* __restrict__ outp,
              int npts)
{
    __shared__ __align__(16) short smem[SMEM_EL];
    __shared__ int cls_cnt;
    const int t = threadIdx.x;

    // ---- input dtype self-detection ----
    if (t == 0) cls_cnt = 0;
    __syncthreads();
    {
        unsigned short w = ((const unsigned short*)xv)[2 * t];
        int e = (w >> 7) & 0xFF;
        if (e >= 110 && e <= 140) atomicAdd(&cls_cnt, 1);
    }
    __syncthreads();
    const bool isbf = (cls_cnt >= 256);

    auto ldw = [&](const void* p, int idx) -> short {
        if (isbf) return ((const short*)p)[idx];
        return bf2s(__float2bfloat16(((const float*)p)[idx]));
    };

    // ---- stage weights transposed: sW[n][k] = W[k][n] ----
    for (int i = t; i < 2048; i += 512) { int k = i >> 6, n = i & 63; smem[OFF_W0T  + n*40 + k] = ldw(Ws0, i); }
    for (int i = t; i < 4096; i += 512) { int k = i >> 6, n = i & 63; smem[OFF_W1T  + n*72 + k] = ldw(Ws1, i); }
    for (int i = t; i < 1024; i += 512) { int k = i >> 4, n = i & 15; smem[OFF_W2T  + n*72 + k] = ldw(Ws2, i); }
    // Wc0: rows 0..31 at k=row (d); rows 32..46 at k=row+1 (geo, shifted);
    // k=32 and k>=48 zero. Absorbs the geo feature shift so the color-net
    // k in [32,64) B-fragment equals the raw redist of the sigma L3 tile.
    for (int i = t; i < 4096; i += 512) {
        int n = i >> 6, k = i & 63;
        short v = 0;
        if (k < 32)                 v = ldw(Wc0, k*64 + n);
        else if (k >= 33 && k < 48) v = ldw(Wc0, (k-1)*64 + n);
        smem[OFF_WC0T + n*72 + k] = v;
    }
    for (int i = t; i < 4096; i += 512) { int k = i >> 6, n = i & 63; smem[OFF_WC1T + n*72 + k] = ldw(Wc1, i); }
    for (int i = t; i < 4096; i += 512) { int k = i >> 6, n = i & 63; smem[OFF_WC2T + n*72 + k] = ldw(Wc2, i); }
    for (int i = t; i < 1024; i += 512) { int n = i >> 6, k = i & 63; smem[OFF_WC3T + n*72 + k] = (n < 3) ? ldw(Wc3, k*3 + n) : (short)0; }
    __syncthreads();

    const int lane = t & 63;
    const int wv   = t >> 6;
    const int m16  = lane & 15;   // point within 16-tile (B/D column)
    const int q    = lane >> 4;   // quad: k-group for A/B, feature-row-group for D

    const f4v zf = {0.f, 0.f, 0.f, 0.f};

    auto loadRow8f = [&](const void* p, int eoff) -> s8v {
        const float* f = (const float*)p + eoff;
        f4v f0 = *(const f4v*)f;
        f4v f1 = *(const f4v*)(f + 4);
        s8v r;
        #pragma unroll
        for (int j = 0; j < 4; j++) {
            r[j]     = bf2s(__float2bfloat16(f0[j]));
            r[j + 4] = bf2s(__float2bfloat16(f1[j]));
        }
        return r;
    };
    auto putOut = [&](int idx, float v) {
        if (isbf) ((short*)outp)[idx] = bf2s(__float2bfloat16(v));
        else      ((float*)outp)[idx] = v;
    };

    // hardware packed f32x2 -> bf16x2 (RNE); no builtin on gfx950, use asm
    auto cvtpk = [](float lo, float hi) -> unsigned int {
        unsigned int r;
        asm("v_cvt_pk_bf16_f32 %0, %1, %2" : "=v"(r) : "v"(lo), "v"(hi));
        return r;
    };

    // ---- in-register feature redistribution (relu fused) ----
    auto redist = [&](const f4v (&a)[4], s8v (&fr)[2]) {
        unsigned int P[4][2];
        #pragma unroll
        for (int kt = 0; kt < 4; kt++)
            #pragma unroll
            for (int rp = 0; rp < 2; rp++)
                P[kt][rp] = cvtpk(fmaxf(a[kt][2*rp], 0.f), fmaxf(a[kt][2*rp+1], 0.f));
        #pragma unroll
        for (int a2 = 0; a2 < 2; a2++)
            #pragma unroll
            for (int rp = 0; rp < 2; rp++) {
                asm("v_permlane32_swap_b32 %0, %1" : "+v"(P[2*a2][rp]), "+v"(P[2*a2+1][rp]));
                asm("v_permlane16_swap_b32 %0, %1" : "+v"(P[2*a2][rp]), "+v"(P[2*a2+1][rp]));
            }
        #pragma unroll
        for (int kc = 0; kc < 2; kc++) {
            union { unsigned int u[4]; s8v v; } fu;
            fu.u[0] = P[2*kc][0];     fu.u[1] = P[2*kc][1];
            fu.u[2] = P[2*kc + 1][0]; fu.u[3] = P[2*kc + 1][1];
            fr[kc] = fu.v;
        }
    };
    // junction: only the kc=1 fragment of redist with all kt slots = s
    auto redistHalf = [&](const f4v s, s8v &frHi) {
        unsigned int P2[2], P3[2];
        #pragma unroll
        for (int rp = 0; rp < 2; rp++) {
            P2[rp] = cvtpk(fmaxf(s[2*rp], 0.f), fmaxf(s[2*rp+1], 0.f));
            P3[rp] = P2[rp];
        }
        #pragma unroll
        for (int rp = 0; rp < 2; rp++) {
            asm("v_permlane32_swap_b32 %0, %1" : "+v"(P2[rp]), "+v"(P3[rp]));
            asm("v_permlane16_swap_b32 %0, %1" : "+v"(P2[rp]), "+v"(P3[rp]));
        }
        union { unsigned int u[4]; s8v v; } fu;
        fu.u[0] = P2[0]; fu.u[1] = P2[1]; fu.u[2] = P3[0]; fu.u[3] = P3[1];
        frHi = fu.v;
    };

    // 64-out transposed layer for BOTH tiles: each LDS fragment feeds 8 MFMAs
    auto layerT2 = [&](int woff, const s8v (&bfr)[2][2][2], f4v (&out)[2][2][4]) {
        #pragma unroll
        for (int kt = 0; kt < 4; kt++) {
            s8v a0 = *(const s8v*)(smem + woff + (kt*16 + m16)*72 + q*8);
            s8v a1 = *(const s8v*)(smem + woff + (kt*16 + m16)*72 + 32 + q*8);
            #pragma unroll
            for (int u = 0; u < 2; u++)
                #pragma unroll
                for (int pt = 0; pt < 2; pt++)
                    out[u][pt][kt] = MFMA_BF16(a1, bfr[u][pt][1],
                                     MFMA_BF16(a0, bfr[u][pt][0], zf, 0,0,0), 0,0,0);
        }
    };

    const int ntiles = npts / 32;
    const int nw     = gridDim.x * 8;   // 4096 waves
    int base = blockIdx.x * 8 + wv;

    #pragma unroll 1
    for (; base < ntiles; base += 2 * nw) {
        const int tA   = base;
        const int tB   = base + nw;
        const bool hasB = tB < ntiles;
        const int tl[2] = { tA, hasB ? tB : tA };   // clamped for loads

        // ---- load both tiles' x ----
        s8v xb[2][2];
        #pragma unroll
        for (int u = 0; u < 2; u++)
            #pragma unroll
            for (int pt = 0; pt < 2; pt++) {
                const int off = (tl[u]*32 + pt*16 + m16)*32 + q*8;
                xb[u][pt] = isbf ? *(const s8v*)((const short*)xv + off)
                                 : loadRow8f(xv, off);
            }

        f4v acc[2][2][4];
        s8v bfr[2][2][2];

        // ---------------- sigma net (transposed, 2 tiles interleaved) ----------------
        // L1: H1^T = Ws0^T(64x32) @ X^T(32x32)
        #pragma unroll
        for (int kt = 0; kt < 4; kt++) {
            s8v a0 = *(const s8v*)(smem + OFF_W0T + (kt*16 + m16)*40 + q*8);
            #pragma unroll
            for (int u = 0; u < 2; u++)
                #pragma unroll
                for (int pt = 0; pt < 2; pt++)
                    acc[u][pt][kt] = MFMA_BF16(a0, xb[u][pt], zf, 0,0,0);
        }
        #pragma unroll
        for (int u = 0; u < 2; u++)
            #pragma unroll
            for (int pt = 0; pt < 2; pt++) redist(acc[u][pt], bfr[u][pt]);

        // L2
        layerT2(OFF_W1T, bfr, acc);
        #pragma unroll
        for (int u = 0; u < 2; u++)
            #pragma unroll
            for (int pt = 0; pt < 2; pt++) redist(acc[u][pt], bfr[u][pt]);

        // issue d loads now (acc dead); latency hides under L3 + junction
        s8v db[2][2];
        #pragma unroll
        for (int u = 0; u < 2; u++)
            #pragma unroll
            for (int pt = 0; pt < 2; pt++) {
                const int off = (tl[u]*32 + pt*16 + m16)*32 + q*8;
                db[u][pt] = isbf ? *(const s8v*)((const short*)dv + off)
                                 : loadRow8f(dv, off);
            }

        // L3: H3^T(16x32) = Ws2^T(16x64) @ H2^T
        f4v s3[2][2];
        {
            s8v c0 = *(const s8v*)(smem + OFF_W2T + m16*72 + q*8);
            s8v c1 = *(const s8v*)(smem + OFF_W2T + m16*72 + 32 + q*8);
            #pragma unroll
            for (int u = 0; u < 2; u++)
                #pragma unroll
                for (int pt = 0; pt < 2; pt++)
                    s3[u][pt] = MFMA_BF16(c1, bfr[u][pt][1],
                                MFMA_BF16(c0, bfr[u][pt][0], zf, 0,0,0), 0,0,0);
        }

        // sigma out: feature 0 = lanes q==0, r==0
        if (q == 0) {
            #pragma unroll
            for (int u = 0; u < 2; u++)
                if (u == 0 || hasB) {
                    #pragma unroll
                    for (int pt = 0; pt < 2; pt++)
                        putOut(3*npts + tl[u]*32 + pt*16 + m16, fmaxf(s3[u][pt][0], 0.f));
                }
        }

        // ---------------- junction (no LDS) ----------------
        #pragma unroll
        for (int u = 0; u < 2; u++)
            #pragma unroll
            for (int pt = 0; pt < 2; pt++) {
                redistHalf(s3[u][pt], bfr[u][pt][1]);
                bfr[u][pt][0] = db[u][pt];
            }

        // ---------------- color net ----------------
        // C0: Hc1^T = Wc0^T @ [d | geo]^T
        layerT2(OFF_WC0T, bfr, acc);
        #pragma unroll
        for (int u = 0; u < 2; u++)
            #pragma unroll
            for (int pt = 0; pt < 2; pt++) redist(acc[u][pt], bfr[u][pt]);

        // C1
        layerT2(OFF_WC1T, bfr, acc);
        #pragma unroll
        for (int u = 0; u < 2; u++)
            #pragma unroll
            for (int pt = 0; pt < 2; pt++) redist(acc[u][pt], bfr[u][pt]);

        // C2
        layerT2(OFF_WC2T, bfr, acc);
        #pragma unroll
        for (int u = 0; u < 2; u++)
            #pragma unroll
            for (int pt = 0; pt < 2; pt++) redist(acc[u][pt], bfr[u][pt]);

        // C3: RGB^T(16x32) = Wc3^T(16x64) @ Hc3^T
        f4v c7[2][2];
        {
            s8v e0 = *(const s8v*)(smem + OFF_WC3T + m16*72 + q*8);
            s8v e1 = *(const s8v*)(smem + OFF_WC3T + m16*72 + 32 + q*8);
            #pragma unroll
            for (int u = 0; u < 2; u++)
                #pragma unroll
                for (int pt = 0; pt < 2; pt++)
                    c7[u][pt] = MFMA_BF16(e1, bfr[u][pt][1],
                                MFMA_BF16(e0, bfr[u][pt][0], zf, 0,0,0), 0,0,0);
        }
        if (q == 0) {
            #pragma unroll
            for (int u = 0; u < 2; u++)
                if (u == 0 || hasB) {
                    #pragma unroll
                    for (int pt = 0; pt < 2; pt++) {
                        const int bout = (tl[u]*32 + pt*16 + m16) * 3;
                        #pragma unroll
                        for (int r = 0; r < 3; r++) {
                            float v  = c7[u][pt][r];
                            float sg = 1.0f / (1.0f + __expf(-v));
                            putOut(bout + r, sg);
                        }
                    }
                }
        }
    }
}

extern "C" void kernel_launch(void* const* d_in, const int* in_sizes, int n_in,
                              void* d_out, int out_size, void* d_ws, size_t ws_size,
                              hipStream_t stream) {
    const int npts = in_sizes[0] / 32;
    // 512 blocks x 512 thr (grid-512 restores the clean 131MB FETCH baseline);
    // 46.6 KB LDS + <=128 VGPR -> 2 blocks/CU, 16 waves/CU, 4 waves/SIMD.
    // Each wave interleaves TWO tile-chains: 8192 tiles in flight, 4 iterations.
    rf_fused<<<512, 512, 0, stream>>>(d_in[0], d_in[1], d_in[2], d_in[3], d_in[4],
                                      d_in[5], d_in[6], d_in[7], d_in[8],
                                      d_out, npts);
}

// Round 6
// 311.980 us; speedup vs baseline: 1.0843x; 1.0234x over previous
//
#include <hip/hip_runtime.h>
#include <hip/hip_bf16.h>

typedef short s8v  __attribute__((ext_vector_type(8)));
typedef float f4v  __attribute__((ext_vector_type(4)));
typedef float f16v __attribute__((ext_vector_type(16)));

#define MFMA32 __builtin_amdgcn_mfma_f32_32x32x16_bf16

// LDS element offsets (16-bit elements). Weights only; activations in regs.
constexpr int OFF_W0T  = 0;      // [64][40]  Ws0^T, k<32
constexpr int OFF_W1T  = 2560;   // [64][72]  Ws1^T
constexpr int OFF_W2T  = 7168;   // [32][72]  Ws2^T, rows>=16 zero
constexpr int OFF_WC0T = 9472;   // [64][72]  Wc0^T: k<32=d, k=32 zero,
                                 //           k in [33,48)=geo shifted, k>=48 zero
constexpr int OFF_WC1T = 14080;  // [64][72]
constexpr int OFF_WC2T = 18688;  // [64][72]
constexpr int OFF_WC3T = 23296;  // [32][72]  rows>=3 zero
constexpr int SMEM_EL  = 25600;  // 51200 B

static __device__ __forceinline__ short bf2s(__hip_bfloat16 h) {
    union { __hip_bfloat16 b; short s; } u; u.b = h; return u.s;
}

__global__ __launch_bounds__(512, 4)
void rf_fused(const void* __restrict__ xv,
              const void* __restrict__ dv,
              const void* __restrict__ Ws0,
              const void* __restrict__ Ws1,
              const void* __restrict__ Ws2,
              const void* __restrict__ Wc0,
              const void* __restrict__ Wc1,
              const void* __restrict__ Wc2,
              const void* __restrict__ Wc3,
              void* __restrict__ outp,
              int npts)
{
    __shared__ __align__(16) short smem[SMEM_EL];
    __shared__ int cls_cnt;
    const int t = threadIdx.x;

    // ---- input dtype self-detection ----
    if (t == 0) cls_cnt = 0;
    __syncthreads();
    {
        unsigned short w = ((const unsigned short*)xv)[2 * t];
        int e = (w >> 7) & 0xFF;
        if (e >= 110 && e <= 140) atomicAdd(&cls_cnt, 1);
    }
    __syncthreads();
    const bool isbf = (cls_cnt >= 256);

    auto ldw = [&](const void* p, int idx) -> short {
        if (isbf) return ((const short*)p)[idx];
        return bf2s(__float2bfloat16(((const float*)p)[idx]));
    };

    // ---- stage weights transposed: sW[n][k] = W[k][n] ----
    for (int i = t; i < 2048; i += 512) { int k = i >> 6, n = i & 63; smem[OFF_W0T + n*40 + k] = ldw(Ws0, i); }
    for (int i = t; i < 4096; i += 512) { int k = i >> 6, n = i & 63; smem[OFF_W1T + n*72 + k] = ldw(Ws1, i); }
    // Ws2^T padded to 32 rows (rows 16..31 zero)
    for (int i = t; i < 2048; i += 512) {
        int n = i >> 6, k = i & 63;
        smem[OFF_W2T + n*72 + k] = (n < 16) ? ldw(Ws2, k*16 + n) : (short)0;
    }
    // Wc0: rows 0..31 at k=row (d); rows 32..46 at k=row+1 (geo, shifted);
    // k=32 and k>=48 zero. Absorbs the geo feature shift.
    for (int i = t; i < 4096; i += 512) {
        int n = i >> 6, k = i & 63;
        short v = 0;
        if (k < 32)                 v = ldw(Wc0, k*64 + n);
        else if (k >= 33 && k < 48) v = ldw(Wc0, (k-1)*64 + n);
        smem[OFF_WC0T + n*72 + k] = v;
    }
    for (int i = t; i < 4096; i += 512) { int k = i >> 6, n = i & 63; smem[OFF_WC1T + n*72 + k] = ldw(Wc1, i); }
    for (int i = t; i < 4096; i += 512) { int k = i >> 6, n = i & 63; smem[OFF_WC2T + n*72 + k] = ldw(Wc2, i); }
    // Wc3^T padded to 32 rows (rows 3..31 zero)
    for (int i = t; i < 2048; i += 512) {
        int n = i >> 6, k = i & 63;
        smem[OFF_WC3T + n*72 + k] = (n < 3) ? ldw(Wc3, k*3 + n) : (short)0;
    }
    __syncthreads();

    const int lane = t & 63;
    const int wv   = t >> 6;
    const int l5   = lane & 31;   // point (B/D col) or out-feature (A row)
    const int hi   = lane >> 5;   // k-half selector
    const f16v zf16 = {0.f,0.f,0.f,0.f,0.f,0.f,0.f,0.f,
                       0.f,0.f,0.f,0.f,0.f,0.f,0.f,0.f};

    // hoist L3 weight fragments (loop-invariant)
    s8v w2f[4];
    #pragma unroll
    for (int kc = 0; kc < 4; kc++)
        w2f[kc] = *(const s8v*)(smem + OFF_W2T + l5*72 + kc*16 + hi*8);

    auto loadRow8f = [&](const void* p, int eoff) -> s8v {
        const float* f = (const float*)p + eoff;
        f4v f0 = *(const f4v*)f;
        f4v f1 = *(const f4v*)(f + 4);
        s8v r;
        #pragma unroll
        for (int j = 0; j < 4; j++) {
            r[j]     = bf2s(__float2bfloat16(f0[j]));
            r[j + 4] = bf2s(__float2bfloat16(f1[j]));
        }
        return r;
    };
    auto putOut = [&](int idx, float v) {
        if (isbf) ((short*)outp)[idx] = bf2s(__float2bfloat16(v));
        else      ((float*)outp)[idx] = v;
    };
    auto cvtpk = [](float lo, float hiV) -> unsigned int {
        unsigned int r;
        asm("v_cvt_pk_bf16_f32 %0, %1, %2" : "=v"(r) : "v"(lo), "v"(hiV));
        return r;
    };
    auto swap32 = [](unsigned int &x, unsigned int &y) {
        asm("v_permlane32_swap_b32 %0, %1" : "+v"(x), "+v"(y));
    };

    // ---- redistribution: 32x32 D acc (2 m-tiles = 64 feats) -> 4 B-frags ----
    // Source: feature f = 32*t + 8*(reg>>2) + 4*hi + (reg&3) (one point/lane).
    // Dest: frag c element j = bf16 of feature 16c + 8*hi + j.
    // As u32 pairs g=f>>1: source bits (g4=t, g3g2=a, g1=hi, g0=e);
    // dest (g4g3=c, g2=hi, g1g0=slot). One permlane32_swap per (t,A,e) pair
    // transposes (g2 <-> lane-hi). relu fused into the cvtpk inputs.
    auto redist32 = [&](const f16v &a0, const f16v &a1, s8v (&fr)[4]) {
        unsigned int Q[2][4][2];
        #pragma unroll
        for (int tt = 0; tt < 2; tt++) {
            const f16v &a = tt ? a1 : a0;
            #pragma unroll
            for (int aa = 0; aa < 4; aa++)
                #pragma unroll
                for (int e = 0; e < 2; e++)
                    Q[tt][aa][e] = cvtpk(fmaxf(a[4*aa + 2*e], 0.f),
                                         fmaxf(a[4*aa + 2*e + 1], 0.f));
        }
        #pragma unroll
        for (int tt = 0; tt < 2; tt++)
            #pragma unroll
            for (int A = 0; A < 2; A++)
                #pragma unroll
                for (int e = 0; e < 2; e++)
                    swap32(Q[tt][2*A][e], Q[tt][2*A + 1][e]);
        #pragma unroll
        for (int c = 0; c < 4; c++) {
            const int tt = c >> 1, A = c & 1;
            union { unsigned int u[4]; s8v v; } fu;
            fu.u[0] = Q[tt][2*A][0];     fu.u[1] = Q[tt][2*A][1];
            fu.u[2] = Q[tt][2*A + 1][0]; fu.u[3] = Q[tt][2*A + 1][1];
            fr[c] = fu.v;
        }
    };
    // junction: 16-feat tile (regs 0..7 hold feats 0..15) -> one B-frag
    auto redistJ = [&](const f16v &a, s8v &fg) {
        unsigned int Q[2][2];
        #pragma unroll
        for (int aa = 0; aa < 2; aa++)
            #pragma unroll
            for (int e = 0; e < 2; e++)
                Q[aa][e] = cvtpk(fmaxf(a[4*aa + 2*e], 0.f),
                                 fmaxf(a[4*aa + 2*e + 1], 0.f));
        #pragma unroll
        for (int e = 0; e < 2; e++) swap32(Q[0][e], Q[1][e]);
        union { unsigned int u[4]; s8v v; } fu;
        fu.u[0] = Q[0][0]; fu.u[1] = Q[0][1];
        fu.u[2] = Q[1][0]; fu.u[3] = Q[1][1];
        fg = fu.v;
    };

    // 64-out layer: A = W^T from LDS, B = activation frags, K=64 (4 chained MFMAs)
    auto layer64 = [&](int woff, const s8v (&b)[4], f16v (&o)[2]) {
        #pragma unroll
        for (int mt = 0; mt < 2; mt++) {
            f16v c = zf16;
            #pragma unroll
            for (int kc = 0; kc < 4; kc++) {
                s8v a = *(const s8v*)(smem + woff + (mt*32 + l5)*72 + kc*16 + hi*8);
                c = MFMA32(a, b[kc], c, 0, 0, 0);
            }
            o[mt] = c;
        }
    };

    const int ntiles = npts / 32;
    const int nw     = gridDim.x * 8;   // 4096 waves
    int tile = blockIdx.x * 8 + wv;

    auto loadB2 = [&](const void* p, int r0, s8v (&f)[2]) {
        #pragma unroll
        for (int kc = 0; kc < 2; kc++) {
            const int off = (r0 + l5)*32 + kc*16 + hi*8;
            f[kc] = isbf ? *(const s8v*)((const short*)p + off) : loadRow8f(p, off);
        }
    };

    s8v xb[2];
    if (tile < ntiles) loadB2(xv, tile*32, xb);

    #pragma unroll 1
    for (; tile < ntiles; tile += nw) {
        const int r0  = tile * 32;
        const int nxt = tile + nw;

        // d for this tile: latency hides under sigma net + junction
        s8v db[2];
        loadB2(dv, r0, db);

        // ---------------- sigma net ----------------
        // L1: H1^T(64x32) = Ws0^T @ X^T, K=32
        f16v h[2];
        #pragma unroll
        for (int mt = 0; mt < 2; mt++) {
            f16v c = zf16;
            #pragma unroll
            for (int kc = 0; kc < 2; kc++) {
                s8v a = *(const s8v*)(smem + OFF_W0T + (mt*32 + l5)*40 + kc*16 + hi*8);
                c = MFMA32(a, xb[kc], c, 0, 0, 0);
            }
            h[mt] = c;
        }

        // xb consumed: prefetch next tile's x
        s8v xbn[2];
        if (nxt < ntiles) loadB2(xv, nxt*32, xbn);

        s8v bfr[4];
        redist32(h[0], h[1], bfr);

        // L2
        layer64(OFF_W1T, bfr, h);
        redist32(h[0], h[1], bfr);

        // L3: 16 real out-feats (rows 16..31 of A are zero)
        f16v s3 = zf16;
        #pragma unroll
        for (int kc = 0; kc < 4; kc++)
            s3 = MFMA32(w2f[kc], bfr[kc], s3, 0, 0, 0);

        // sigma = relu(feat 0): reg 0 at lanes hi==0, point = l5
        if (hi == 0) putOut(3*npts + r0 + l5, fmaxf(s3[0], 0.f));

        // junction: geo feats into the k in [32,48) B-frag (k=32 row is zero)
        s8v geo;
        redistJ(s3, geo);

        // ---------------- color net ----------------
        // C0: k<32 = d, k in [32,48) = geo, k>=48 zero rows (skipped)
        #pragma unroll
        for (int mt = 0; mt < 2; mt++) {
            const int base = OFF_WC0T + (mt*32 + l5)*72;
            f16v c = zf16;
            c = MFMA32(*(const s8v*)(smem + base +  0 + hi*8), db[0], c, 0, 0, 0);
            c = MFMA32(*(const s8v*)(smem + base + 16 + hi*8), db[1], c, 0, 0, 0);
            c = MFMA32(*(const s8v*)(smem + base + 32 + hi*8), geo,   c, 0, 0, 0);
            h[mt] = c;
        }
        redist32(h[0], h[1], bfr);

        // C1
        layer64(OFF_WC1T, bfr, h);
        redist32(h[0], h[1], bfr);

        // C2
        layer64(OFF_WC2T, bfr, h);
        redist32(h[0], h[1], bfr);

        // C3: rgb = rows 0..2 (rows 3..31 of A zero)
        f16v c7 = zf16;
        #pragma unroll
        for (int kc = 0; kc < 4; kc++) {
            s8v a = *(const s8v*)(smem + OFF_WC3T + l5*72 + kc*16 + hi*8);
            c7 = MFMA32(a, bfr[kc], c7, 0, 0, 0);
        }
        if (hi == 0) {
            const int base = (r0 + l5) * 3;
            #pragma unroll
            for (int r = 0; r < 3; r++) {
                float sg = 1.0f / (1.0f + __expf(-c7[r]));
                putOut(base + r, sg);
            }
        }

        xb[0] = xbn[0]; xb[1] = xbn[1];
    }
}

extern "C" void kernel_launch(void* const* d_in, const int* in_sizes, int n_in,
                              void* d_out, int out_size, void* d_ws, size_t ws_size,
                              hipStream_t stream) {
    const int npts = in_sizes[0] / 32;
    // 512 blocks x 512 thr; 51.2 KB LDS, <=128 VGPR -> 2 blocks/CU, 16 waves/CU.
    // One 32-point tile per wave per iteration, 8 iterations, zero tail.
    rf_fused<<<512, 512, 0, stream>>>(d_in[0], d_in[1], d_in[2], d_in[3], d_in[4],
                                      d_in[5], d_in[6], d_in[7], d_in[8],
                                      d_out, npts);
}